// Round 1
// baseline (220.037 us; speedup 1.0000x reference)
//
#include <hip/hip_runtime.h>
#include <stdint.h>
#include <stddef.h>

#define DIM 1024
#define EPS 1e-8f

typedef __attribute__((ext_vector_type(8))) __bf16 bf16x8;
typedef __attribute__((ext_vector_type(4))) float f32x4;

__device__ __forceinline__ unsigned short f32_to_bf16(float f) {
    unsigned int u = __float_as_uint(f);
    u += 0x7FFFu + ((u >> 16) & 1u);   // round-to-nearest-even
    return (unsigned short)(u >> 16);
}

// async global->LDS, 16B per lane, wave-uniform LDS base + lane*16
__device__ __forceinline__ void async_copy16(const void* g, void* l) {
    __builtin_amdgcn_global_load_lds(
        (__attribute__((address_space(1))) void*)const_cast<void*>(g),
        (__attribute__((address_space(3))) void*)(l), 16, 0, 0);
}

// ---------------------------------------------------------------------------
// Prep: per-row norm; write unit-normalized bf16 row; (optionally) exact sim.
// grid = rows, block = 256 (each thread owns 4 contiguous elements).
// ---------------------------------------------------------------------------
template <bool HAS_POS>
__global__ __launch_bounds__(256)
void prep_kernel(const float* __restrict__ src, const float* __restrict__ pos,
                 unsigned short* __restrict__ dstb, float* __restrict__ simOut) {
    const int row  = blockIdx.x;
    const int tid  = threadIdx.x;
    const int lane = tid & 63;
    const int wave = tid >> 6;

    const float4 xv = ((const float4*)(src + (size_t)row * DIM))[tid];
    float sxx = xv.x * xv.x + xv.y * xv.y + xv.z * xv.z + xv.w * xv.w;
    float spp = 0.f, sxp = 0.f;
    if (HAS_POS) {
        const float4 pv = ((const float4*)(pos + (size_t)row * DIM))[tid];
        spp = pv.x * pv.x + pv.y * pv.y + pv.z * pv.z + pv.w * pv.w;
        sxp = xv.x * pv.x + xv.y * pv.y + xv.z * pv.z + xv.w * pv.w;
    }
#pragma unroll
    for (int off = 32; off > 0; off >>= 1) {
        sxx += __shfl_down(sxx, off);
        if (HAS_POS) {
            spp += __shfl_down(spp, off);
            sxp += __shfl_down(sxp, off);
        }
    }
    __shared__ float red[3][4];
    __shared__ float bcast;
    if (lane == 0) {
        red[0][wave] = sxx;
        if (HAS_POS) { red[1][wave] = spp; red[2][wave] = sxp; }
    }
    __syncthreads();
    if (tid == 0) {
        float nx = sqrtf(red[0][0] + red[0][1] + red[0][2] + red[0][3]);
        bcast = (nx > 0.f) ? (1.f / nx) : 0.f;
        if (HAS_POS) {
            float np = sqrtf(red[1][0] + red[1][1] + red[1][2] + red[1][3]);
            float dp = red[2][0] + red[2][1] + red[2][2] + red[2][3];
            simOut[row] = dp / fmaxf(nx * np, EPS);
        }
    }
    __syncthreads();
    const float inv = bcast;
    ushort4 o;
    o.x = f32_to_bf16(xv.x * inv);
    o.y = f32_to_bf16(xv.y * inv);
    o.z = f32_to_bf16(xv.z * inv);
    o.w = f32_to_bf16(xv.w * inv);
    ((ushort4*)(dstb + (size_t)row * DIM))[tid] = o;
}

// ---------------------------------------------------------------------------
// Fused GEMM: rowsum[i] += sum_j exp( Xn[i,:] . Nn[j,:] )  (both unit rows)
// 128x128 tile, BK=64, 4 waves, each wave 4x4 of 16x16x32 bf16 MFMAs.
// LDS layout: row-major [128][64] bf16 with 16B chunks XOR-swizzled by row&7
// (staging via global_load_lds forbids padding; swizzle kills bank conflicts).
// ---------------------------------------------------------------------------
__global__ __launch_bounds__(256)
void gemm_exp_rowsum(const unsigned short* __restrict__ Xn,
                     const unsigned short* __restrict__ Nn,
                     float* __restrict__ rowsum) {
    constexpr int K  = DIM;  // 1024
    constexpr int BK = 64;   // k-elements per stage (128 B per row)
    __shared__ __align__(16) unsigned short Ash[128 * BK];
    __shared__ __align__(16) unsigned short Bsh[128 * BK];

    const int tid  = threadIdx.x;
    const int lane = tid & 63;
    const int wave = tid >> 6;
    const int rowBase = blockIdx.y * 128;
    const int colBase = blockIdx.x * 128;

    // staging: one global_load_lds covers 8 rows x 128B; lane -> (row, chunk)
    const int srow   = lane >> 3;              // 0..7
    const int schunk = (lane & 7) ^ srow;      // XOR-swizzled 16B-chunk index
    const unsigned short* gA = Xn + (size_t)(rowBase + wave * 8 + srow) * K + schunk * 8;
    const unsigned short* gB = Nn + (size_t)(colBase + wave * 8 + srow) * K + schunk * 8;
    unsigned short* lA = &Ash[(wave * 8) * BK];
    unsigned short* lB = &Bsh[(wave * 8) * BK];

    const f32x4 fz = {0.f, 0.f, 0.f, 0.f};
    f32x4 acc[4][4];
#pragma unroll
    for (int mi = 0; mi < 4; mi++)
#pragma unroll
        for (int ni = 0; ni < 4; ni++) acc[mi][ni] = fz;

    const int m0   = (wave >> 1) * 64;   // wave's row block within tile
    const int n0   = (wave & 1) * 64;    // wave's col block within tile
    const int quad = lane >> 4;          // 0..3
    const int mrow = lane & 15;          // fragment row/col index
    const int skey = mrow & 7;           // read-side swizzle key

    for (int k0 = 0; k0 < K; k0 += BK) {
        __syncthreads();  // prev compute done before overwrite
#pragma unroll
        for (int i = 0; i < 4; i++) {
            async_copy16(gA + (size_t)(i * 32) * K + k0, lA + i * 32 * BK);
            async_copy16(gB + (size_t)(i * 32) * K + k0, lB + i * 32 * BK);
        }
        __syncthreads();  // staging visible (compiler drains vmcnt)

#pragma unroll
        for (int ks = 0; ks < 2; ks++) {
            const int ck = ks * 4 + quad;  // logical 16B chunk 0..7
            bf16x8 af[4], bf[4];
#pragma unroll
            for (int mi = 0; mi < 4; mi++)
                af[mi] = *(const bf16x8*)&Ash[(m0 + mi * 16 + mrow) * BK + ((ck ^ skey) * 8)];
#pragma unroll
            for (int ni = 0; ni < 4; ni++)
                bf[ni] = *(const bf16x8*)&Bsh[(n0 + ni * 16 + mrow) * BK + ((ck ^ skey) * 8)];
#pragma unroll
            for (int mi = 0; mi < 4; mi++)
#pragma unroll
                for (int ni = 0; ni < 4; ni++)
                    acc[mi][ni] = __builtin_amdgcn_mfma_f32_16x16x32_bf16(
                        af[mi], bf[ni], acc[mi][ni], 0, 0, 0);
        }
    }

    // epilogue: exp + row-reduce. C/D layout: col=lane&15, row=quad*4+reg.
#pragma unroll
    for (int mi = 0; mi < 4; mi++) {
        float rs0 = 0.f, rs1 = 0.f, rs2 = 0.f, rs3 = 0.f;
#pragma unroll
        for (int ni = 0; ni < 4; ni++) {
            rs0 += __expf(acc[mi][ni].x);
            rs1 += __expf(acc[mi][ni].y);
            rs2 += __expf(acc[mi][ni].z);
            rs3 += __expf(acc[mi][ni].w);
        }
#pragma unroll
        for (int off = 1; off < 16; off <<= 1) {   // reduce over 16 cols
            rs0 += __shfl_xor(rs0, off);
            rs1 += __shfl_xor(rs1, off);
            rs2 += __shfl_xor(rs2, off);
            rs3 += __shfl_xor(rs3, off);
        }
        if ((lane & 15) == 0) {
            const int r = rowBase + m0 + mi * 16 + quad * 4;
            atomicAdd(&rowsum[r + 0], rs0);
            atomicAdd(&rowsum[r + 1], rs1);
            atomicAdd(&rowsum[r + 2], rs2);
            atomicAdd(&rowsum[r + 3], rs3);
        }
    }
}

__global__ void zero_kernel(float* __restrict__ p, int n) {
    int i = blockIdx.x * blockDim.x + threadIdx.x;
    if (i < n) p[i] = 0.f;
}

__global__ __launch_bounds__(256)
void loss_kernel(const float* __restrict__ rowsum, const float* __restrict__ sim,
                 float* __restrict__ out, int bn) {
    const int tid  = threadIdx.x;
    const int lane = tid & 63;
    const int wave = tid >> 6;
    float acc = 0.f;
    for (int i = tid; i < bn; i += 256) acc += logf(rowsum[i]) - sim[i];
#pragma unroll
    for (int off = 32; off > 0; off >>= 1) acc += __shfl_down(acc, off);
    __shared__ float red[4];
    if (lane == 0) red[wave] = acc;
    __syncthreads();
    if (tid == 0) out[0] = (red[0] + red[1] + red[2] + red[3]) / (float)bn;
}

extern "C" void kernel_launch(void* const* d_in, const int* in_sizes, int n_in,
                              void* d_out, int out_size, void* d_ws, size_t ws_size,
                              hipStream_t stream) {
    const float* x   = (const float*)d_in[0];
    const float* pos = (const float*)d_in[1];
    const float* neg = (const float*)d_in[2];
    const int bn = in_sizes[0] / DIM;  // 4096
    const int cn = in_sizes[2] / DIM;  // 8192

    // ws layout: Xn bf16 [bn*DIM] | Nn bf16 [cn*DIM] | sim f32 [bn] | rowsum f32 [bn]
    unsigned short* Xn = (unsigned short*)d_ws;
    unsigned short* Nn = Xn + (size_t)bn * DIM;
    float* sim    = (float*)(Nn + (size_t)cn * DIM);
    float* rowsum = sim + bn;

    zero_kernel<<<dim3((bn + 255) / 256), dim3(256), 0, stream>>>(rowsum, bn);
    prep_kernel<true><<<dim3(bn), dim3(256), 0, stream>>>(x, pos, Xn, sim);
    prep_kernel<false><<<dim3(cn), dim3(256), 0, stream>>>(neg, nullptr, Nn, nullptr);
    gemm_exp_rowsum<<<dim3(cn / 128, bn / 128), dim3(256), 0, stream>>>(Xn, Nn, rowsum);
    loss_kernel<<<dim3(1), dim3(256), 0, stream>>>(rowsum, sim, (float*)d_out, bn);
}

// Round 2
// 218.076 us; speedup vs baseline: 1.0090x; 1.0090x over previous
//
#include <hip/hip_runtime.h>
#include <stdint.h>
#include <stddef.h>

#define DIM 1024
#define EPS 1e-8f

typedef __attribute__((ext_vector_type(8))) __bf16 bf16x8;
typedef __attribute__((ext_vector_type(4))) float f32x4;

__device__ __forceinline__ unsigned short f32_to_bf16(float f) {
    unsigned int u = __float_as_uint(f);
    u += 0x7FFFu + ((u >> 16) & 1u);   // round-to-nearest-even
    return (unsigned short)(u >> 16);
}

// async global->LDS, 16B per lane, wave-uniform LDS base + lane*16
__device__ __forceinline__ void async_copy16(const void* g, void* l) {
    __builtin_amdgcn_global_load_lds(
        (__attribute__((address_space(1))) void*)const_cast<void*>(g),
        (__attribute__((address_space(3))) void*)(l), 16, 0, 0);
}

// ---------------------------------------------------------------------------
// Prep: wave-per-row, NO barriers. Each wave: row sum-of-squares via
// shfl_xor reduce, then write unit-normalized bf16 row. HAS_POS also emits
// the exact fp32 positive cosine sim and zeroes rowsum[row].
// grid = nrows/4 blocks of 256 (4 independent waves).
// ---------------------------------------------------------------------------
template <bool HAS_POS>
__global__ __launch_bounds__(256)
void prep_kernel(const float* __restrict__ src, const float* __restrict__ pos,
                 unsigned short* __restrict__ dstb, float* __restrict__ simOut,
                 float* __restrict__ rowsum) {
    const int lane = threadIdx.x & 63;
    const int wave = threadIdx.x >> 6;
    const int row  = blockIdx.x * 4 + wave;

    const float4* s = (const float4*)(src + (size_t)row * DIM);
    float4 xv[4], pv[4];
    float sxx = 0.f, spp = 0.f, sxp = 0.f;
#pragma unroll
    for (int i = 0; i < 4; i++) {
        xv[i] = s[lane + 64 * i];
        sxx += xv[i].x * xv[i].x + xv[i].y * xv[i].y + xv[i].z * xv[i].z + xv[i].w * xv[i].w;
    }
    if (HAS_POS) {
        const float4* p = (const float4*)(pos + (size_t)row * DIM);
#pragma unroll
        for (int i = 0; i < 4; i++) {
            pv[i] = p[lane + 64 * i];
            spp += pv[i].x * pv[i].x + pv[i].y * pv[i].y + pv[i].z * pv[i].z + pv[i].w * pv[i].w;
            sxp += xv[i].x * pv[i].x + xv[i].y * pv[i].y + xv[i].z * pv[i].z + xv[i].w * pv[i].w;
        }
    }
#pragma unroll
    for (int off = 1; off < 64; off <<= 1) {
        sxx += __shfl_xor(sxx, off);
        if (HAS_POS) {
            spp += __shfl_xor(spp, off);
            sxp += __shfl_xor(sxp, off);
        }
    }
    const float nx  = sqrtf(sxx);
    const float inv = (nx > 0.f) ? (1.f / nx) : 0.f;
    if (HAS_POS && lane == 0) {
        const float np = sqrtf(spp);
        simOut[row] = sxp / fmaxf(nx * np, EPS);
        rowsum[row] = 0.f;
    }
    ushort4* d = (ushort4*)(dstb + (size_t)row * DIM);
#pragma unroll
    for (int i = 0; i < 4; i++) {
        ushort4 o;
        o.x = f32_to_bf16(xv[i].x * inv);
        o.y = f32_to_bf16(xv[i].y * inv);
        o.z = f32_to_bf16(xv[i].z * inv);
        o.w = f32_to_bf16(xv[i].w * inv);
        d[lane + 64 * i] = o;
    }
}

// ---------------------------------------------------------------------------
// Fused GEMM: rowsum[i] += sum_j exp( Xn[i,:] . Nn[j,:] )  (unit rows, bf16)
// 128x128 tile, BK=32, double-buffered LDS, ONE barrier per K-iter:
//   barrier (drains prefetch issued one compute-phase ago) -> issue prefetch
//   into other buffer -> compute current buffer.
// LDS rows are 64B = 4x16B chunks, XOR-swizzled by (row&3) on the GLOBAL
// side (global_load_lds dest is fixed base+lane*16), read back with the
// matching chunk^=(row&3) -> conflict-free ds_read_b128.
// ---------------------------------------------------------------------------
__global__ __launch_bounds__(256)
void gemm_exp_rowsum(const unsigned short* __restrict__ Xn,
                     const unsigned short* __restrict__ Nn,
                     float* __restrict__ rowsum) {
    constexpr int K   = DIM;   // 1024
    constexpr int BK  = 32;    // k-elements per stage (64 B per row)
    constexpr int NIT = K / BK;  // 32
    __shared__ __align__(16) unsigned short Ash[2][128 * BK];
    __shared__ __align__(16) unsigned short Bsh[2][128 * BK];

    const int tid  = threadIdx.x;
    const int lane = tid & 63;
    const int wave = tid >> 6;
    const int rowBase = blockIdx.y * 128;
    const int colBase = blockIdx.x * 128;

    // staging map: one glds instr = 1KB = 16 rows x 64B; lane -> (row, chunk)
    const int srow   = lane >> 2;                    // 0..15
    const int schunk = (lane & 3) ^ (srow & 3);      // XOR-swizzled 16B chunk
    const unsigned short* gA = Xn + (size_t)(rowBase + wave * 16 + srow) * K + schunk * 8;
    const unsigned short* gB = Nn + (size_t)(colBase + wave * 16 + srow) * K + schunk * 8;
    const int lgrp0 = (wave * 16) * BK;              // wave's 16-row group
    const int lgrp1 = (wave * 16 + 64) * BK;         // +64 rows group

    const f32x4 fz = {0.f, 0.f, 0.f, 0.f};
    f32x4 acc[4][4];
#pragma unroll
    for (int mi = 0; mi < 4; mi++)
#pragma unroll
        for (int ni = 0; ni < 4; ni++) acc[mi][ni] = fz;

    const int m0   = (wave >> 1) * 64;
    const int n0   = (wave & 1) * 64;
    const int quad = lane >> 4;
    const int mrow = lane & 15;
    const int ckx  = (quad ^ (mrow & 3)) * 8;        // physical chunk (ushorts)

    int aoff[4], boff[4];
#pragma unroll
    for (int i = 0; i < 4; i++) {
        aoff[i] = (m0 + i * 16 + mrow) * BK + ckx;
        boff[i] = (n0 + i * 16 + mrow) * BK + ckx;
    }

#define STAGE(buf, it)                                                   \
    do {                                                                 \
        const int kq = (it) * BK;                                        \
        async_copy16(gA + kq,            &Ash[buf][lgrp0]);              \
        async_copy16(gA + 64 * K + kq,   &Ash[buf][lgrp1]);              \
        async_copy16(gB + kq,            &Bsh[buf][lgrp0]);              \
        async_copy16(gB + 64 * K + kq,   &Bsh[buf][lgrp1]);              \
    } while (0)

#define COMPUTE(buf)                                                     \
    do {                                                                 \
        bf16x8 af[4], bf[4];                                             \
        _Pragma("unroll")                                                \
        for (int i = 0; i < 4; i++) {                                    \
            af[i] = *(const bf16x8*)&Ash[buf][aoff[i]];                  \
            bf[i] = *(const bf16x8*)&Bsh[buf][boff[i]];                  \
        }                                                                \
        _Pragma("unroll")                                                \
        for (int mi = 0; mi < 4; mi++)                                   \
            _Pragma("unroll")                                            \
            for (int ni = 0; ni < 4; ni++)                               \
                acc[mi][ni] = __builtin_amdgcn_mfma_f32_16x16x32_bf16(   \
                    af[mi], bf[ni], acc[mi][ni], 0, 0, 0);               \
    } while (0)

    STAGE(0, 0);
    for (int it = 0; it < NIT; it += 2) {
        __syncthreads();              // drains prefetch for buf0 (1 phase old)
        STAGE(1, it + 1);             // prefetch next while computing current
        COMPUTE(0);
        __syncthreads();              // drains prefetch for buf1
        if (it + 2 < NIT) STAGE(0, it + 2);
        COMPUTE(1);
    }
#undef STAGE
#undef COMPUTE

    // epilogue: exp + row-reduce. C/D layout: col=lane&15, row=quad*4+reg.
#pragma unroll
    for (int mi = 0; mi < 4; mi++) {
        float rs0 = 0.f, rs1 = 0.f, rs2 = 0.f, rs3 = 0.f;
#pragma unroll
        for (int ni = 0; ni < 4; ni++) {
            rs0 += __expf(acc[mi][ni].x);
            rs1 += __expf(acc[mi][ni].y);
            rs2 += __expf(acc[mi][ni].z);
            rs3 += __expf(acc[mi][ni].w);
        }
#pragma unroll
        for (int off = 1; off < 16; off <<= 1) {   // reduce over 16 cols
            rs0 += __shfl_xor(rs0, off);
            rs1 += __shfl_xor(rs1, off);
            rs2 += __shfl_xor(rs2, off);
            rs3 += __shfl_xor(rs3, off);
        }
        if ((lane & 15) == 0) {
            const int r = rowBase + m0 + mi * 16 + quad * 4;
            atomicAdd(&rowsum[r + 0], rs0);
            atomicAdd(&rowsum[r + 1], rs1);
            atomicAdd(&rowsum[r + 2], rs2);
            atomicAdd(&rowsum[r + 3], rs3);
        }
    }
}

__global__ __launch_bounds__(1024)
void loss_kernel(const float* __restrict__ rowsum, const float* __restrict__ sim,
                 float* __restrict__ out, int bn) {
    const int tid  = threadIdx.x;
    const int lane = tid & 63;
    const int wave = tid >> 6;
    float acc = 0.f;
    for (int i = tid; i < bn; i += 1024) acc += logf(rowsum[i]) - sim[i];
#pragma unroll
    for (int off = 1; off < 64; off <<= 1) acc += __shfl_xor(acc, off);
    __shared__ float red[16];
    if (lane == 0) red[wave] = acc;
    __syncthreads();
    if (tid == 0) {
        float t = 0.f;
#pragma unroll
        for (int i = 0; i < 16; i++) t += red[i];
        out[0] = t / (float)bn;
    }
}

extern "C" void kernel_launch(void* const* d_in, const int* in_sizes, int n_in,
                              void* d_out, int out_size, void* d_ws, size_t ws_size,
                              hipStream_t stream) {
    const float* x   = (const float*)d_in[0];
    const float* pos = (const float*)d_in[1];
    const float* neg = (const float*)d_in[2];
    const int bn = in_sizes[0] / DIM;  // 4096
    const int cn = in_sizes[2] / DIM;  // 8192

    // ws layout: Xn bf16 [bn*DIM] | Nn bf16 [cn*DIM] | sim f32 [bn] | rowsum f32 [bn]
    unsigned short* Xn = (unsigned short*)d_ws;
    unsigned short* Nn = Xn + (size_t)bn * DIM;
    float* sim    = (float*)(Nn + (size_t)cn * DIM);
    float* rowsum = sim + bn;

    prep_kernel<true><<<dim3(bn / 4), dim3(256), 0, stream>>>(x, pos, Xn, sim, rowsum);
    prep_kernel<false><<<dim3(cn / 4), dim3(256), 0, stream>>>(neg, nullptr, Nn, nullptr, nullptr);
    gemm_exp_rowsum<<<dim3(cn / 128, bn / 128), dim3(256), 0, stream>>>(Xn, Nn, rowsum);
    loss_kernel<<<dim3(1), dim3(1024), 0, stream>>>(rowsum, sim, (float*)d_out, bn);
}